// Round 8
// baseline (149.888 us; speedup 1.0000x reference)
//
#include <hip/hip_runtime.h>
#include <hip/hip_bf16.h>

// Problem constants
#define DD    256        // descriptor dim
#define KK    64         // clusters
#define NPIX  262144     // H*W
#define NW    256        // n-window (per window)
#define NWIN  4          // windows per block
#define GRID  256        // GRID * NWIN * NW == NPIX ; 1 block per CU
#define BLOCK 1024       // 16 waves: 8 producer (P1) + 8 consumer (P2)

// LDS strides (elements)
#define W_S   264        // W:    [64][264] bf16 (row 528 B, 16B-mult)
#define AB_S  264        // abar: [64][264] bf16 per buffer (row 528 B)
#define XC_S  40         // phase-1 slice rows: 40 shorts = 80 B (16B-mult)
#define SV_S  129        // V stage: [64][129] f32 (half of d at a time)

typedef __attribute__((ext_vector_type(8))) short bf16x8;
typedef __attribute__((ext_vector_type(4))) float f32x4;

union Frag { bf16x8 v; int i[4]; };

__device__ __forceinline__ int cvtpk(float a, float b) {
    // packed f32->bf16 RNE; lowers to v_cvt_pk_bf16_f32 on gfx950
    __hip_bfloat162 h = __float22bfloat162_rn(float2{a, b});
    int r; __builtin_memcpy(&r, &h, 4); return r;  // low short = a
}

// lgkm-only barrier: LDS visibility without draining in-flight global loads
__device__ __forceinline__ void lds_barrier() {
    asm volatile("s_waitcnt lgkmcnt(0)" ::: "memory");
    __builtin_amdgcn_s_barrier();
}

__global__ __launch_bounds__(BLOCK, 4)   // cap 128 VGPR; (.,8) is allocator poison
void netvlad_fused(const float* __restrict__ x, const float* __restrict__ conv_w,
                   const float* __restrict__ conv_b, float* __restrict__ Vpart,
                   float* __restrict__ asum_part)
{
    __shared__ short Wl[KK * W_S];        // 33792 B
    __shared__ short Ab[2][KK * AB_S];    // 67584 B (double-buffered abar)
    __shared__ float asb[2][8][KK];       //  4096 B (double-buffered wave asum)
    __shared__ union {
        short slice[8 * 32 * XC_S];       // 20480 B: 8 producer-private 32x40 slices
        float sv[KK * SV_S];              // 33024 B: epilogue staging
    } U2;
    // total 138496 B -> 1 block/CU

    const int t    = threadIdx.x;
    const int lane = t & 63;
    const int w    = t >> 6;        // wave 0..15
    const int l15  = lane & 15;
    const int q    = (lane >> 4) & 3;
    const int bid  = blockIdx.x;
    const size_t n0 = (size_t)bid * (NWIN * NW);

    const bool producer = (w < 8);
    const int  cw = w - 8;          // consumer index 0..7

    // ---- producer load mapping: 32-col private slice, chunks of 32 d ----
    const int dg = lane >> 3;            // 0..7  (4 d-rows each)
    const int ng = lane & 7;             // 0..7  (4 n-cols each)
    const size_t nself0 = n0 + 32 * w + 4 * ng;   // producer p = w

    // producer prologue: window-0 chunks 0,1 (overlap W staging)
    float4 pr[2][4];
    if (producer) {
        #pragma unroll
        for (int j = 0; j < 4; ++j)
            pr[0][j] = *(const float4*)(x + (size_t)(4 * dg + j) * NPIX + nself0);
        __builtin_amdgcn_sched_barrier(0);   // pin
    }

    // ---- stage W (fp32 -> bf16) into LDS, all 16 waves ----
    #pragma unroll
    for (int i = 0; i < 16; ++i) {
        int idx = t + BLOCK * i;                 // 0..16383
        float wv = conv_w[idx];
        __hip_bfloat16 hb = __float2bfloat16(wv);
        short s; __builtin_memcpy(&s, &hb, 2);
        Wl[(idx >> 8) * W_S + (idx & 255)] = s;
    }

    if (producer) {
        #pragma unroll
        for (int j = 0; j < 4; ++j)
            pr[1][j] = *(const float4*)(x + (size_t)(32 + 4 * dg + j) * NPIX + nself0);
        __builtin_amdgcn_sched_barrier(0);   // pin
    }

    // consumer persistent accumulators (live across all slots)
    f32x4 acc[2][4];
    #pragma unroll
    for (int rg = 0; rg < 2; ++rg)
        #pragma unroll
        for (int ct = 0; ct < 4; ++ct)
            acc[rg][ct] = (f32x4){0.f, 0.f, 0.f, 0.f};
    float asumReg = 0.f;

    lds_barrier();   // W visible; producer pr loads stay in flight

    // ==================== slot pipeline: 5 slots, 4 windows ====================
    // slot i: producers build window i (i<NWIN) -> Ab[i&1], asb[i&1]
    //         consumers contract window i-1 (i>0) from Ab[(i-1)&1]
    for (int i = 0; i <= NWIN; ++i) {
        if (producer) {
            if (i < NWIN) {
                const size_t nwin   = n0 + (size_t)i * NW;
                const size_t nselfw = nwin + 32 * w + 4 * ng;
                short* slice = &U2.slice[w * (32 * XC_S)];

                f32x4 Lc[2][4];
                #pragma unroll
                for (int nt = 0; nt < 2; ++nt)
                    #pragma unroll
                    for (int mt = 0; mt < 4; ++mt)
                        Lc[nt][mt] = (f32x4){0.f, 0.f, 0.f, 0.f};

                #pragma unroll
                for (int ch = 0; ch < 8; ++ch) {
                    const int cur = ch & 1;

                    // stage pr[cur] -> private slice (n-major micro-transpose)
                    {
                        const float* r0 = (const float*)&pr[cur][0];
                        const float* r1 = (const float*)&pr[cur][1];
                        const float* r2 = (const float*)&pr[cur][2];
                        const float* r3 = (const float*)&pr[cur][3];
                        #pragma unroll
                        for (int c = 0; c < 4; ++c) {
                            int2 pk; pk.x = cvtpk(r0[c], r1[c]); pk.y = cvtpk(r2[c], r3[c]);
                            *(int2*)&slice[(4 * ng + c) * XC_S + 4 * dg] = pk;
                        }
                    }

                    // depth-2 prefetch within window
                    if (ch < 6) {
                        #pragma unroll
                        for (int j = 0; j < 4; ++j)
                            pr[cur][j] = *(const float4*)(x + (size_t)(32 * (ch + 2) + 4 * dg + j) * NPIX + nselfw);
                        __builtin_amdgcn_sched_barrier(0);   // pin
                    }
                    // seam prefetch: next window's chunks 0,1 (pr fully dead at ch==7)
                    if (ch == 7 && i + 1 < NWIN) {
                        const size_t nselfn = nselfw + NW;
                        #pragma unroll
                        for (int j = 0; j < 4; ++j)
                            pr[0][j] = *(const float4*)(x + (size_t)(4 * dg + j) * NPIX + nselfn);
                        #pragma unroll
                        for (int j = 0; j < 4; ++j)
                            pr[1][j] = *(const float4*)(x + (size_t)(32 + 4 * dg + j) * NPIX + nselfn);
                        __builtin_amdgcn_sched_barrier(0);   // pin
                    }

                    // frags + MFMA; A from LDS Wl
                    Frag Bv[2];
                    #pragma unroll
                    for (int nt = 0; nt < 2; ++nt)
                        Bv[nt] = *(const Frag*)&slice[(16 * nt + l15) * XC_S + 8 * q];
                    #pragma unroll
                    for (int mt = 0; mt < 4; ++mt) {
                        Frag A = *(const Frag*)&Wl[(16 * mt + l15) * W_S + 32 * ch + 8 * q];
                        #pragma unroll
                        for (int nt = 0; nt < 2; ++nt)
                            Lc[nt][mt] = __builtin_amdgcn_mfma_f32_16x16x32_bf16(A.v, Bv[nt].v, Lc[nt][mt], 0, 0, 0);
                    }
                }

                // softmax over k (in-register, wave-local); breg reloaded per window (L1-hot)
                #pragma unroll
                for (int nt = 0; nt < 2; ++nt) {
                    float mx = -1e30f;
                    #pragma unroll
                    for (int mt = 0; mt < 4; ++mt)
                        #pragma unroll
                        for (int r = 0; r < 4; ++r) {
                            Lc[nt][mt][r] += conv_b[16 * mt + 4 * q + r];
                            mx = fmaxf(mx, Lc[nt][mt][r]);
                        }
                    mx = fmaxf(mx, __shfl_xor(mx, 16));
                    mx = fmaxf(mx, __shfl_xor(mx, 32));
                    float s = 0.f;
                    #pragma unroll
                    for (int mt = 0; mt < 4; ++mt)
                        #pragma unroll
                        for (int r = 0; r < 4; ++r) {
                            float e = __expf(Lc[nt][mt][r] - mx);
                            Lc[nt][mt][r] = e;
                            s += e;
                        }
                    s += __shfl_xor(s, 16);
                    s += __shfl_xor(s, 32);
                    float inv = 1.0f / s;
                    #pragma unroll
                    for (int mt = 0; mt < 4; ++mt)
                        #pragma unroll
                        for (int r = 0; r < 4; ++r)
                            Lc[nt][mt][r] *= inv;
                }

                // wave asum partial -> asb[i&1][p][k]
                #pragma unroll
                for (int mt = 0; mt < 4; ++mt)
                    #pragma unroll
                    for (int r = 0; r < 4; ++r) {
                        float v = Lc[0][mt][r] + Lc[1][mt][r];
                        v += __shfl_xor(v, 1);
                        v += __shfl_xor(v, 2);
                        v += __shfl_xor(v, 4);
                        v += __shfl_xor(v, 8);
                        if (l15 == 0) asb[i & 1][w][16 * mt + 4 * q + r] = v;
                    }

                // abar -> Ab[i&1] (bf16), producer-private columns
                #pragma unroll
                for (int nt = 0; nt < 2; ++nt)
                    #pragma unroll
                    for (int mt = 0; mt < 4; ++mt)
                        #pragma unroll
                        for (int r = 0; r < 4; ++r) {
                            __hip_bfloat16 hb = __float2bfloat16(Lc[nt][mt][r]);
                            short s; __builtin_memcpy(&s, &hb, 2);
                            Ab[i & 1][(16 * mt + 4 * q + r) * AB_S + 32 * w + 16 * nt + l15] = s;
                        }
            }
            // slot NWIN: producers idle (consumers drain)
        } else {
            if (i > 0) {
                const int win = i - 1;
                const size_t nwin = n0 + (size_t)win * NW;
                const short* ab = Ab[win & 1];
                const float* xr0 = x + (size_t)(32 * cw + l15) * NPIX + nwin + 8 * q;
                const float* xr1 = xr0 + (size_t)16 * NPIX;

                // prologue: depth-2 (L3-hot; window-start latency accepted)
                float4 pv[2][2][2];   // [depth][rg][half]
                #pragma unroll
                for (int d = 0; d < 2; ++d) {
                    pv[d][0][0] = *(const float4*)(xr0 + 32 * d);
                    pv[d][0][1] = *(const float4*)(xr0 + 32 * d + 4);
                    pv[d][1][0] = *(const float4*)(xr1 + 32 * d);
                    pv[d][1][1] = *(const float4*)(xr1 + 32 * d + 4);
                }
                __builtin_amdgcn_sched_barrier(0);   // pin prologue issue

                #pragma unroll
                for (int s = 0; s < 8; ++s) {
                    const int cur = s & 1;
                    Frag Af[2];
                    #pragma unroll
                    for (int rg = 0; rg < 2; ++rg) {
                        Af[rg].i[0] = cvtpk(pv[cur][rg][0].x, pv[cur][rg][0].y);
                        Af[rg].i[1] = cvtpk(pv[cur][rg][0].z, pv[cur][rg][0].w);
                        Af[rg].i[2] = cvtpk(pv[cur][rg][1].x, pv[cur][rg][1].y);
                        Af[rg].i[3] = cvtpk(pv[cur][rg][1].z, pv[cur][rg][1].w);
                    }
                    if (s < 6) {   // depth-2 prefetch
                        pv[cur][0][0] = *(const float4*)(xr0 + 32 * (s + 2));
                        pv[cur][0][1] = *(const float4*)(xr0 + 32 * (s + 2) + 4);
                        pv[cur][1][0] = *(const float4*)(xr1 + 32 * (s + 2));
                        pv[cur][1][1] = *(const float4*)(xr1 + 32 * (s + 2) + 4);
                        __builtin_amdgcn_sched_barrier(0);   // pin
                    }
                    Frag Bf[4];
                    #pragma unroll
                    for (int ct = 0; ct < 4; ++ct)
                        Bf[ct] = *(const Frag*)&ab[(16 * ct + l15) * AB_S + 32 * s + 8 * q];
                    #pragma unroll
                    for (int ct = 0; ct < 4; ++ct) {
                        acc[0][ct] = __builtin_amdgcn_mfma_f32_16x16x32_bf16(Af[0].v, Bf[ct].v, acc[0][ct], 0, 0, 0);
                        acc[1][ct] = __builtin_amdgcn_mfma_f32_16x16x32_bf16(Af[1].v, Bf[ct].v, acc[1][ct], 0, 0, 0);
                    }
                }

                // wave 8 accumulates block asum for this window
                if (w == 8) {
                    #pragma unroll
                    for (int pp = 0; pp < 8; ++pp)
                        asumReg += asb[win & 1][pp][lane];
                }
            }
            // slot 0: consumers idle (pipeline fill)
        }
        lds_barrier();   // Ab[i&1]/asb[i&1] published; in-flight global loads preserved
    }

    // ---- epilogue: consumer V -> LDS halves -> plain coalesced stores ----
    // acc element (rg, ct, r): k = 16ct + l15, d = 32cw + 16rg + 4q + r
    if (w == 8) asum_part[(size_t)bid * KK + lane] = asumReg;

    float* vout = Vpart + (size_t)bid * (KK * DD);
    #pragma unroll
    for (int H = 0; H < 2; ++H) {
        __syncthreads();
        if (!producer) {
            #pragma unroll
            for (int rg = 0; rg < 2; ++rg) {
                const int dbase = 32 * cw + 16 * rg;
                if ((dbase >> 7) == H) {
                    #pragma unroll
                    for (int ct = 0; ct < 4; ++ct)
                        #pragma unroll
                        for (int r = 0; r < 4; ++r) {
                            int k  = 16 * ct + l15;
                            int dl = dbase + 4 * q + r - 128 * H;
                            U2.sv[k * SV_S + dl] = acc[rg][ct][r];
                        }
                }
            }
        }
        __syncthreads();
        #pragma unroll
        for (int ii = 0; ii < 8; ++ii) {
            int idx = t + BLOCK * ii;       // 0..8191
            int k = idx >> 7, dl = idx & 127;
            vout[k * DD + 128 * H + dl] = U2.sv[k * SV_S + dl];
        }
    }
}

__global__ __launch_bounds__(256)
void netvlad_reduce(const float* __restrict__ Vpart, const float* __restrict__ asum_part,
                    float* __restrict__ Vred, float* __restrict__ asum_red)
{
    __shared__ float sbuf[256];
    const int t = threadIdx.x;
    if (blockIdx.x < 256) {
        const int o = blockIdx.x * 64 + (t & 63);
        const int g = t >> 6;
        float s = 0.f;
        #pragma unroll 8
        for (int i = 0; i < 64; ++i)
            s += Vpart[(size_t)(g * 64 + i) * (KK * DD) + o];
        sbuf[t] = s;
        __syncthreads();
        if (t < 64) Vred[o] = sbuf[t] + sbuf[t + 64] + sbuf[t + 128] + sbuf[t + 192];
    } else {
        const int k = t & 63;
        const int g = t >> 6;
        float s = 0.f;
        #pragma unroll 8
        for (int i = 0; i < 64; ++i)
            s += asum_part[(size_t)(g * 64 + i) * KK + k];
        sbuf[t] = s;
        __syncthreads();
        if (t < 64) asum_red[k] = sbuf[t] + sbuf[t + 64] + sbuf[t + 128] + sbuf[t + 192];
    }
}

__global__ __launch_bounds__(1024)
void netvlad_finalize(const float* __restrict__ Vws, const float* __restrict__ asum_ws,
                      const float* __restrict__ c, float* __restrict__ y)
{
    __shared__ float sV[KK * DD];
    __shared__ float sa[KK];
    __shared__ float colf[DD];
    __shared__ float rowf[KK];
    const int t = threadIdx.x;

    if (t < KK) sa[t] = asum_ws[t];
    __syncthreads();

    #pragma unroll
    for (int i = 0; i < 16; ++i) {
        int idx = t + 1024 * i;
        sV[idx] = Vws[idx] - c[idx] * sa[idx >> 8];
    }
    __syncthreads();

    if (t < DD) {   // column (d) norms over k
        float s = 0.f;
        for (int k = 0; k < KK; ++k) { float v = sV[k * DD + t]; s += v * v; }
        colf[t] = 1.0f / fmaxf(sqrtf(s), 1e-12f);
    }
    __syncthreads();

    #pragma unroll
    for (int i = 0; i < 16; ++i) {
        int idx = t + 1024 * i;
        sV[idx] *= colf[idx & 255];
    }
    __syncthreads();

    {   // row (k) norms over d: 16 threads per row
        int k = t >> 4, p = t & 15;
        float s = 0.f;
        #pragma unroll
        for (int j = 0; j < 16; ++j) { float v = sV[k * DD + p + 16 * j]; s += v * v; }
        s += __shfl_xor(s, 1);
        s += __shfl_xor(s, 2);
        s += __shfl_xor(s, 4);
        s += __shfl_xor(s, 8);
        if (p == 0) rowf[k] = 1.0f / fmaxf(sqrtf(s), 1e-12f);
    }
    __syncthreads();

    #pragma unroll
    for (int i = 0; i < 16; ++i) {
        int idx = t + 1024 * i;
        y[idx] = sV[idx] * rowf[idx >> 8];
    }
}

extern "C" void kernel_launch(void* const* d_in, const int* in_sizes, int n_in,
                              void* d_out, int out_size, void* d_ws, size_t ws_size,
                              hipStream_t stream) {
    const float* x      = (const float*)d_in[0];
    const float* c      = (const float*)d_in[1];
    const float* conv_w = (const float*)d_in[2];
    const float* conv_b = (const float*)d_in[3];
    float* y = (float*)d_out;

    // workspace: 256*16384 + 256*64 + 16384 + 64 floats (~16.9 MB)
    float* Vpart     = (float*)d_ws;
    float* asum_part = Vpart + (size_t)GRID * KK * DD;
    float* Vred      = asum_part + (size_t)GRID * KK;
    float* asum_red  = Vred + KK * DD;

    // no memset needed: all partials are fully overwritten with plain stores
    netvlad_fused<<<GRID, BLOCK, 0, stream>>>(x, conv_w, conv_b, Vpart, asum_part);
    netvlad_reduce<<<257, 256, 0, stream>>>(Vpart, asum_part, Vred, asum_red);
    netvlad_finalize<<<1, 1024, 0, stream>>>(Vred, asum_red, c, y);
}

// Round 10
// 106.125 us; speedup vs baseline: 1.4124x; 1.4124x over previous
//
#include <hip/hip_runtime.h>
#include <hip/hip_bf16.h>

// Problem constants
#define DD    256        // descriptor dim
#define KK    64         // clusters
#define NPIX  262144     // H*W
#define NW    256        // n-window (per window)
#define NWIN  4          // windows per block
#define GRID  256        // GRID * NWIN * NW == NPIX ; 1 block per CU
#define BLOCK 1024       // 16 uniform waves; P1(i) and P2(i-1) interleaved per wave

// LDS strides (elements)
#define W_S   264        // W:    [64][264] bf16 (row 528 B, 16B-mult)
#define AB_S  264        // abar: [64][264] bf16 per buffer (row 528 B)
#define XC_S  40         // phase-1 slice rows: 40 shorts = 80 B (16B-mult)
#define SV_S  129        // V stage: [64][129] f32 (half of d at a time)

typedef __attribute__((ext_vector_type(8))) short bf16x8;
typedef __attribute__((ext_vector_type(4))) float f32x4;

union Frag { bf16x8 v; int i[4]; };

__device__ __forceinline__ int cvtpk(float a, float b) {
    // packed f32->bf16 RNE; lowers to v_cvt_pk_bf16_f32 on gfx950
    __hip_bfloat162 h = __float22bfloat162_rn(float2{a, b});
    int r; __builtin_memcpy(&r, &h, 4); return r;  // low short = a
}

// lgkm-only barrier: LDS visibility without draining in-flight global loads
__device__ __forceinline__ void lds_barrier() {
    asm volatile("s_waitcnt lgkmcnt(0)" ::: "memory");
    __builtin_amdgcn_s_barrier();
}

// amdgpu_waves_per_eu(4,4): pin allocator budget to 128 VGPR. The default
// heuristic snaps to 64 and SPILLS when live state exceeds it (R8: 131 MB
// of scratch writes). With 1 block of 16 waves/CU, occupancy is 4 waves/EU
// regardless, so the 128-reg budget is free.
__global__ __attribute__((amdgpu_flat_work_group_size(BLOCK, BLOCK), amdgpu_waves_per_eu(4, 4)))
void netvlad_fused(const float* __restrict__ x, const float* __restrict__ conv_w,
                   const float* __restrict__ conv_b, float* __restrict__ Vpart,
                   float* __restrict__ asum_part)
{
    __shared__ short Wl[KK * W_S];        // 33792 B
    __shared__ short Ab[2][KK * AB_S];    // 67584 B (double-buffered abar)
    __shared__ float asb[2][16][KK];      //  8192 B (double-buffered wave asum)
    __shared__ union {
        short slice[16 * 16 * XC_S];      // 20480 B: 16 wave-private 16x40 slices
        float sv[KK * SV_S];              // 33024 B: epilogue staging
    } U2;
    // total 142592 B -> 1 block/CU

    const int t    = threadIdx.x;
    const int lane = t & 63;
    const int w    = t >> 6;        // wave 0..15
    const int l15  = lane & 15;
    const int q    = (lane >> 4) & 3;
    const int bid  = blockIdx.x;
    const size_t n0 = (size_t)bid * (NWIN * NW);

    // ---- P1 load mapping: wave-private 16-col slice, chunks of 32 d ----
    const int p  = lane >> 2;            // 0..15 (d-pair)
    const int ng = lane & 3;             // 0..3  (4 n-cols each)
    const size_t nself0 = n0 + 16 * w + 4 * ng;   // window 0

    // ---- P2 row base: lane l15 owns d-row 16w+l15 ----
    const float* xrow_base = x + (size_t)(16 * w + l15) * NPIX + n0 + 8 * q;

    // prologue: window-0 chunks 0,1 (overlap W staging)
    float4 pr[2][2];
    #pragma unroll
    for (int j = 0; j < 2; ++j)
        pr[0][j] = *(const float4*)(x + (size_t)(2 * p + j) * NPIX + nself0);
    __builtin_amdgcn_sched_barrier(0);   // pin

    // ---- stage W (fp32 -> bf16) into LDS, once ----
    #pragma unroll
    for (int i = 0; i < 16; ++i) {
        int idx = t + BLOCK * i;                 // 0..16383
        float wv = conv_w[idx];
        __hip_bfloat16 hb = __float2bfloat16(wv);
        short s; __builtin_memcpy(&s, &hb, 2);
        Wl[(idx >> 8) * W_S + (idx & 255)] = s;
    }

    #pragma unroll
    for (int j = 0; j < 2; ++j)
        pr[1][j] = *(const float4*)(x + (size_t)(32 + 2 * p + j) * NPIX + nself0);
    __builtin_amdgcn_sched_barrier(0);   // pin

    // persistent state
    f32x4 acc[4];
    #pragma unroll
    for (int ct = 0; ct < 4; ++ct) acc[ct] = (f32x4){0.f, 0.f, 0.f, 0.f};
    float asumReg = 0.f;
    float4 pv[2][2];   // P2 pipeline regs (prologue issued one slot ahead)

    lds_barrier();   // W visible; pr loads stay in flight

    // ============ slot pipeline: slot i = P1(win i) ∥ P2(win i-1) ============
    for (int i = 0; i <= NWIN; ++i) {
        const int ib = i & 1;        // P1 publish buffer
        const int pb = ib ^ 1;       // P2 consume buffer ((i-1)&1)

        // asum gather from previous slot (t<64; separate asb -> no slice race)
        if (i > 0 && t < KK) {
            float s = 0.f;
            #pragma unroll
            for (int ww = 0; ww < 16; ++ww) s += asb[pb][ww][t];
            asumReg += s;
        }

        const size_t nwin   = n0 + (size_t)i * NW;       // P1 window
        const size_t nselfw = nwin + 16 * w + 4 * ng;
        const float* xroww  = xrow_base + (size_t)(i - 1) * NW;   // P2 window (i>0)
        short* slice = &U2.slice[w * (16 * XC_S)];

        f32x4 Lc[4];
        #pragma unroll
        for (int mt = 0; mt < 4; ++mt) Lc[mt] = (f32x4){0.f, 0.f, 0.f, 0.f};

        // -------- fused loop: 8 chunks of P1 + 8 steps of P2, interleaved ----
        #pragma unroll
        for (int ch = 0; ch < 8; ++ch) {
            const int cur = ch & 1;

            if (i < NWIN) {
                // P1: stage pr[cur] -> private slice (n-major micro-transpose)
                const float* r0 = (const float*)&pr[cur][0];   // d = 2p
                const float* r1 = (const float*)&pr[cur][1];   // d = 2p+1
                #pragma unroll
                for (int c = 0; c < 4; ++c) {
                    int pk = cvtpk(r0[c], r1[c]);
                    *(int*)&slice[(4 * ng + c) * XC_S + 2 * p] = pk;
                }
                // depth-2 prefetch within window
                if (ch < 6) {
                    #pragma unroll
                    for (int j = 0; j < 2; ++j)
                        pr[cur][j] = *(const float4*)(x + (size_t)(32 * (ch + 2) + 2 * p + j) * NPIX + nselfw);
                    __builtin_amdgcn_sched_barrier(0);   // pin
                }
            }

            if (i > 0) {
                // P2 step s=ch on window i-1: A-frag from registers, B from Ab[pb]
                Frag Af;
                Af.i[0] = cvtpk(pv[cur][0].x, pv[cur][0].y);
                Af.i[1] = cvtpk(pv[cur][0].z, pv[cur][0].w);
                Af.i[2] = cvtpk(pv[cur][1].x, pv[cur][1].y);
                Af.i[3] = cvtpk(pv[cur][1].z, pv[cur][1].w);
                if (ch < 6) {   // depth-2 prefetch (L3-hot)
                    pv[cur][0] = *(const float4*)(xroww + 32 * (ch + 2));
                    pv[cur][1] = *(const float4*)(xroww + 32 * (ch + 2) + 4);
                    __builtin_amdgcn_sched_barrier(0);   // pin
                }
                Frag Bf[4];
                #pragma unroll
                for (int ct = 0; ct < 4; ++ct)
                    Bf[ct] = *(const Frag*)&Ab[pb][(16 * ct + l15) * AB_S + 32 * ch + 8 * q];
                #pragma unroll
                for (int ct = 0; ct < 4; ++ct)
                    acc[ct] = __builtin_amdgcn_mfma_f32_16x16x32_bf16(Af.v, Bf[ct].v, acc[ct], 0, 0, 0);
            }

            if (i < NWIN) {
                // P1: B-frag from slice, A from Wl, 4 MFMA
                Frag Bv = *(const Frag*)&slice[l15 * XC_S + 8 * q];
                #pragma unroll
                for (int mt = 0; mt < 4; ++mt) {
                    Frag A = *(const Frag*)&Wl[(16 * mt + l15) * W_S + 32 * ch + 8 * q];
                    Lc[mt] = __builtin_amdgcn_mfma_f32_16x16x32_bf16(A.v, Bv.v, Lc[mt], 0, 0, 0);
                }
            }
        }

        if (i < NWIN) {
            // ---- softmax over k (in-register, wave-local); bias from L1 ----
            float mx = -1e30f;
            #pragma unroll
            for (int mt = 0; mt < 4; ++mt)
                #pragma unroll
                for (int r = 0; r < 4; ++r) {
                    Lc[mt][r] += conv_b[16 * mt + 4 * q + r];
                    mx = fmaxf(mx, Lc[mt][r]);
                }
            mx = fmaxf(mx, __shfl_xor(mx, 16));
            mx = fmaxf(mx, __shfl_xor(mx, 32));
            float s = 0.f;
            #pragma unroll
            for (int mt = 0; mt < 4; ++mt)
                #pragma unroll
                for (int r = 0; r < 4; ++r) {
                    float e = __expf(Lc[mt][r] - mx);
                    Lc[mt][r] = e;
                    s += e;
                }
            s += __shfl_xor(s, 16);
            s += __shfl_xor(s, 32);
            float inv = 1.0f / s;
            #pragma unroll
            for (int mt = 0; mt < 4; ++mt)
                #pragma unroll
                for (int r = 0; r < 4; ++r)
                    Lc[mt][r] *= inv;

            // wave asum partial -> asb[ib][w]
            #pragma unroll
            for (int mt = 0; mt < 4; ++mt)
                #pragma unroll
                for (int r = 0; r < 4; ++r) {
                    float v = Lc[mt][r];
                    v += __shfl_xor(v, 1);
                    v += __shfl_xor(v, 2);
                    v += __shfl_xor(v, 4);
                    v += __shfl_xor(v, 8);
                    if (l15 == 0) asb[ib][w][16 * mt + 4 * q + r] = v;
                }

            // abar -> Ab[ib] (bf16), wave-private 16 columns
            #pragma unroll
            for (int mt = 0; mt < 4; ++mt)
                #pragma unroll
                for (int r = 0; r < 4; ++r) {
                    __hip_bfloat16 hb = __float2bfloat16(Lc[mt][r]);
                    short sv_; __builtin_memcpy(&sv_, &hb, 2);
                    Ab[ib][(16 * mt + 4 * q + r) * AB_S + 16 * w + l15] = sv_;
                }

            // seam prefetch: P1 window i+1 chunks 0,1 (pr fully dead)
            if (i + 1 < NWIN) {
                const size_t nselfn = nselfw + NW;
                #pragma unroll
                for (int j = 0; j < 2; ++j)
                    pr[0][j] = *(const float4*)(x + (size_t)(2 * p + j) * NPIX + nselfn);
                #pragma unroll
                for (int j = 0; j < 2; ++j)
                    pr[1][j] = *(const float4*)(x + (size_t)(32 + 2 * p + j) * NPIX + nselfn);
                __builtin_amdgcn_sched_barrier(0);   // pin
            }

            // P2 prologue for window i (consumed next slot), depth-2
            {
                const float* xnext = xrow_base + (size_t)i * NW;
                #pragma unroll
                for (int d = 0; d < 2; ++d) {
                    pv[d][0] = *(const float4*)(xnext + 32 * d);
                    pv[d][1] = *(const float4*)(xnext + 32 * d + 4);
                }
                __builtin_amdgcn_sched_barrier(0);   // pin
            }
        }

        lds_barrier();   // Ab[ib]/asb[ib] published; in-flight globals preserved
    }

    // ---- epilogue: asum + V partial -> LDS halves -> plain coalesced stores ----
    // acc element (ct, r): k = 16ct + l15, d = 16w + 4q + r
    if (t < KK) asum_part[(size_t)bid * KK + t] = asumReg;

    float* vout = Vpart + (size_t)bid * (KK * DD);
    #pragma unroll
    for (int H = 0; H < 2; ++H) {
        __syncthreads();
        if ((w >> 3) == H) {
            #pragma unroll
            for (int ct = 0; ct < 4; ++ct)
                #pragma unroll
                for (int r = 0; r < 4; ++r) {
                    int k  = 16 * ct + l15;
                    int dl = 16 * w + 4 * q + r - 128 * H;
                    U2.sv[k * SV_S + dl] = acc[ct][r];
                }
        }
        __syncthreads();
        #pragma unroll
        for (int ii = 0; ii < 8; ++ii) {
            int idx = t + BLOCK * ii;       // 0..8191
            int k = idx >> 7, dl = idx & 127;
            vout[k * DD + 128 * H + dl] = U2.sv[k * SV_S + dl];
        }
    }
}

__global__ __launch_bounds__(256)
void netvlad_reduce(const float* __restrict__ Vpart, const float* __restrict__ asum_part,
                    float* __restrict__ Vred, float* __restrict__ asum_red)
{
    __shared__ float sbuf[256];
    const int t = threadIdx.x;
    if (blockIdx.x < 256) {
        const int o = blockIdx.x * 64 + (t & 63);
        const int g = t >> 6;
        float s = 0.f;
        #pragma unroll 8
        for (int i = 0; i < 64; ++i)
            s += Vpart[(size_t)(g * 64 + i) * (KK * DD) + o];
        sbuf[t] = s;
        __syncthreads();
        if (t < 64) Vred[o] = sbuf[t] + sbuf[t + 64] + sbuf[t + 128] + sbuf[t + 192];
    } else {
        const int k = t & 63;
        const int g = t >> 6;
        float s = 0.f;
        #pragma unroll 8
        for (int i = 0; i < 64; ++i)
            s += asum_part[(size_t)(g * 64 + i) * KK + k];
        sbuf[t] = s;
        __syncthreads();
        if (t < 64) asum_red[k] = sbuf[t] + sbuf[t + 64] + sbuf[t + 128] + sbuf[t + 192];
    }
}

__global__ __launch_bounds__(1024)
void netvlad_finalize(const float* __restrict__ Vws, const float* __restrict__ asum_ws,
                      const float* __restrict__ c, float* __restrict__ y)
{
    __shared__ float sV[KK * DD];
    __shared__ float sa[KK];
    __shared__ float colf[DD];
    __shared__ float rowf[KK];
    const int t = threadIdx.x;

    if (t < KK) sa[t] = asum_ws[t];
    __syncthreads();

    #pragma unroll
    for (int i = 0; i < 16; ++i) {
        int idx = t + 1024 * i;
        sV[idx] = Vws[idx] - c[idx] * sa[idx >> 8];
    }
    __syncthreads();

    if (t < DD) {   // column (d) norms over k
        float s = 0.f;
        for (int k = 0; k < KK; ++k) { float v = sV[k * DD + t]; s += v * v; }
        colf[t] = 1.0f / fmaxf(sqrtf(s), 1e-12f);
    }
    __syncthreads();

    #pragma unroll
    for (int i = 0; i < 16; ++i) {
        int idx = t + 1024 * i;
        sV[idx] *= colf[idx & 255];
    }
    __syncthreads();

    {   // row (k) norms over d: 16 threads per row
        int k = t >> 4, p = t & 15;
        float s = 0.f;
        #pragma unroll
        for (int j = 0; j < 16; ++j) { float v = sV[k * DD + p + 16 * j]; s += v * v; }
        s += __shfl_xor(s, 1);
        s += __shfl_xor(s, 2);
        s += __shfl_xor(s, 4);
        s += __shfl_xor(s, 8);
        if (p == 0) rowf[k] = 1.0f / fmaxf(sqrtf(s), 1e-12f);
    }
    __syncthreads();

    #pragma unroll
    for (int i = 0; i < 16; ++i) {
        int idx = t + 1024 * i;
        y[idx] = sV[idx] * rowf[idx >> 8];
    }
}

extern "C" void kernel_launch(void* const* d_in, const int* in_sizes, int n_in,
                              void* d_out, int out_size, void* d_ws, size_t ws_size,
                              hipStream_t stream) {
    const float* x      = (const float*)d_in[0];
    const float* c      = (const float*)d_in[1];
    const float* conv_w = (const float*)d_in[2];
    const float* conv_b = (const float*)d_in[3];
    float* y = (float*)d_out;

    // workspace: 256*16384 + 256*64 + 16384 + 64 floats (~16.9 MB)
    float* Vpart     = (float*)d_ws;
    float* asum_part = Vpart + (size_t)GRID * KK * DD;
    float* Vred      = asum_part + (size_t)GRID * KK;
    float* asum_red  = Vred + KK * DD;

    // no memset needed: all partials are fully overwritten with plain stores
    netvlad_fused<<<GRID, BLOCK, 0, stream>>>(x, conv_w, conv_b, Vpart, asum_part);
    netvlad_reduce<<<257, 256, 0, stream>>>(Vpart, asum_part, Vred, asum_red);
    netvlad_finalize<<<1, 1024, 0, stream>>>(Vred, asum_red, c, y);
}

// Round 11
// 84.585 us; speedup vs baseline: 1.7720x; 1.2547x over previous
//
#include <hip/hip_runtime.h>
#include <hip/hip_bf16.h>

// Problem constants
#define DD    256        // descriptor dim
#define KK    64         // clusters
#define NPIX  262144     // H*W
#define NW    128        // n-window
#define NWIN  8          // windows per block
#define GRID  256        // GRID * NWIN * NW == NPIX ; 1 block per CU
#define BLOCK 512        // 8 waves; x-tile lives in LDS -> P2 is LDS-only

// LDS strides (elements)
#define W_S   264        // W:   [64][264] bf16 (row 528 B, 16B-mult)
#define XT_S  132        // x_t: [256][132] bf16 (row 264 B, 8B-mult)
#define AB_S  136        // abar:[64][136] bf16 (row 272 B, 16B-mult)
#define XC_S  40         // slice rows: 40 shorts = 80 B
#define SV_S  257        // full-V staging stride (floats)

typedef __attribute__((ext_vector_type(8))) short bf16x8;
typedef __attribute__((ext_vector_type(4))) float f32x4;

union Frag { bf16x8 v; int i[4]; };

__device__ __forceinline__ int cvtpk(float a, float b) {
    // packed f32->bf16 RNE; lowers to v_cvt_pk_bf16_f32 on gfx950
    __hip_bfloat162 h = __float22bfloat162_rn(float2{a, b});
    int r; __builtin_memcpy(&r, &h, 4); return r;  // low short = a
}

// lgkm-only barrier: LDS visibility without draining in-flight global loads
__device__ __forceinline__ void lds_barrier() {
    asm volatile("s_waitcnt lgkmcnt(0)" ::: "memory");
    __builtin_amdgcn_s_barrier();
}

// waves_per_eu(2,2): 8 waves/CU = exactly 2/EU; pins the register budget to
// 256 so the ~145 live VGPRs never spill (R8: default heuristic snapped to 64
// and spilled 131 MB).
__global__ __attribute__((amdgpu_flat_work_group_size(BLOCK, BLOCK), amdgpu_waves_per_eu(2, 2)))
void netvlad_fused(const float* __restrict__ x, const float* __restrict__ conv_w,
                   const float* __restrict__ conv_b, float* __restrict__ Vpart,
                   float* __restrict__ asum_part)
{
    __shared__ short Wl[KK * W_S];              // 33792 B
    __shared__ short Ab[KK * AB_S];             // 17408 B
    __shared__ float asb[8][KK];                //  2048 B
    __shared__ short slice_mem[8 * 16 * XC_S];  // 10240 B: 8 wave-private 16x40 slices
    __shared__ union {
        short xt[DD * XT_S];                    // 67584 B: bf16 x-tile [d][n] for P2
        float sv[KK * SV_S];                    // 65792 B: epilogue staging (full V)
    } UX;
    // total 131072 B -> 1 block/CU

    const int t    = threadIdx.x;
    const int lane = t & 63;
    const int w    = t >> 6;        // wave 0..7
    const int l15  = lane & 15;
    const int q    = (lane >> 4) & 3;
    const int bid  = blockIdx.x;
    const size_t n0 = (size_t)bid * (NWIN * NW);

    // ---- P1 load mapping: wave-private 16 n-cols, chunks of 32 d ----
    const int p  = lane >> 2;            // 0..15 (d-pair)
    const int ng = lane & 3;             // 0..3  (4 n-cols each)
    const size_t nself0 = n0 + 16 * w + 4 * ng;   // window 0

    // prologue: window-0 chunks 0,1 in flight (depth-4 pipeline, slots 0,1)
    float4 pr[4][2];
    #pragma unroll
    for (int c = 0; c < 2; ++c)
        #pragma unroll
        for (int j = 0; j < 2; ++j)
            pr[c][j] = *(const float4*)(x + (size_t)(32 * c + 2 * p + j) * NPIX + nself0);
    __builtin_amdgcn_sched_barrier(0);   // pin

    // ---- stage W (fp32 -> bf16) into LDS, once ----
    #pragma unroll
    for (int i = 0; i < 32; ++i) {
        int idx = t + BLOCK * i;                 // 0..16383
        float wv = conv_w[idx];
        __hip_bfloat16 hb = __float2bfloat16(wv);
        short s; __builtin_memcpy(&s, &hb, 2);
        Wl[(idx >> 8) * W_S + (idx & 255)] = s;
    }

    // prologue: chunks 2,3 (slots 2,3)
    #pragma unroll
    for (int c = 2; c < 4; ++c)
        #pragma unroll
        for (int j = 0; j < 2; ++j)
            pr[c][j] = *(const float4*)(x + (size_t)(32 * c + 2 * p + j) * NPIX + nself0);
    __builtin_amdgcn_sched_barrier(0);   // pin

    float breg[4][4];
    #pragma unroll
    for (int mt = 0; mt < 4; ++mt)
        #pragma unroll
        for (int r = 0; r < 4; ++r)
            breg[mt][r] = conv_b[16 * mt + 4 * q + r];

    // persistent accumulators
    f32x4 acc[2][4];
    #pragma unroll
    for (int rg = 0; rg < 2; ++rg)
        #pragma unroll
        for (int ct = 0; ct < 4; ++ct)
            acc[rg][ct] = (f32x4){0.f, 0.f, 0.f, 0.f};
    float asumReg = 0.f;

    short* slice = &slice_mem[w * (16 * XC_S)];

    lds_barrier();   // W visible; pr loads stay in flight

    // ================= per-window: A (stage+logits) -> B (VLAD, LDS-only) =====
    for (int i = 0; i < NWIN; ++i) {
        const size_t nselfw = n0 + (size_t)i * NW + 16 * w + 4 * ng;

        f32x4 Lc[4];
        #pragma unroll
        for (int mt = 0; mt < 4; ++mt) Lc[mt] = (f32x4){0.f, 0.f, 0.f, 0.f};

        // ---- phase A: 8 chunks of 32 d ----
        #pragma unroll
        for (int ch = 0; ch < 8; ++ch) {
            const int cur = ch & 3;
            const float* r0 = (const float*)&pr[cur][0];   // x[d=32ch+2p  ][n..n+3]
            const float* r1 = (const float*)&pr[cur][1];   // x[d=32ch+2p+1][n..n+3]

            // stage -> wave-private slice ([n][d] for P1 B-frags), d-pair packing
            #pragma unroll
            for (int c = 0; c < 4; ++c) {
                int pk = cvtpk(r0[c], r1[c]);
                *(int*)&slice[(4 * ng + c) * XC_S + 2 * p] = pk;
            }
            // stage -> shared x-tile ([d][n] for P2 A-frags), n packing
            {
                int2 a; a.x = cvtpk(r0[0], r0[1]); a.y = cvtpk(r0[2], r0[3]);
                *(int2*)&UX.xt[(32 * ch + 2 * p) * XT_S + 16 * w + 4 * ng] = a;
                int2 b; b.x = cvtpk(r1[0], r1[1]); b.y = cvtpk(r1[2], r1[3]);
                *(int2*)&UX.xt[(32 * ch + 2 * p + 1) * XT_S + 16 * w + 4 * ng] = b;
            }

            // depth-4 prefetch: ch<4 -> this window's ch+4; ch>=4 -> next window's ch-4
            if (ch < 4) {
                #pragma unroll
                for (int j = 0; j < 2; ++j)
                    pr[cur][j] = *(const float4*)(x + (size_t)(32 * (ch + 4) + 2 * p + j) * NPIX + nselfw);
                __builtin_amdgcn_sched_barrier(0);   // pin
            } else if (i + 1 < NWIN) {
                #pragma unroll
                for (int j = 0; j < 2; ++j)
                    pr[cur][j] = *(const float4*)(x + (size_t)(32 * (ch - 4) + 2 * p + j) * NPIX + nselfw + NW);
                __builtin_amdgcn_sched_barrier(0);   // pin (stays in flight through phase B)
            }

            // P1 MFMA: logits += W[k][d-chunk] * x[d-chunk][n]
            Frag Bv = *(const Frag*)&slice[l15 * XC_S + 8 * q];
            #pragma unroll
            for (int mt = 0; mt < 4; ++mt) {
                Frag A = *(const Frag*)&Wl[(16 * mt + l15) * W_S + 32 * ch + 8 * q];
                Lc[mt] = __builtin_amdgcn_mfma_f32_16x16x32_bf16(A.v, Bv.v, Lc[mt], 0, 0, 0);
            }
        }

        // ---- softmax over k (in-register, wave-local) ----
        {
            float mx = -1e30f;
            #pragma unroll
            for (int mt = 0; mt < 4; ++mt)
                #pragma unroll
                for (int r = 0; r < 4; ++r) {
                    Lc[mt][r] += breg[mt][r];
                    mx = fmaxf(mx, Lc[mt][r]);
                }
            mx = fmaxf(mx, __shfl_xor(mx, 16));
            mx = fmaxf(mx, __shfl_xor(mx, 32));
            float s = 0.f;
            #pragma unroll
            for (int mt = 0; mt < 4; ++mt)
                #pragma unroll
                for (int r = 0; r < 4; ++r) {
                    float e = __expf(Lc[mt][r] - mx);
                    Lc[mt][r] = e;
                    s += e;
                }
            s += __shfl_xor(s, 16);
            s += __shfl_xor(s, 32);
            float inv = 1.0f / s;
            #pragma unroll
            for (int mt = 0; mt < 4; ++mt)
                #pragma unroll
                for (int r = 0; r < 4; ++r)
                    Lc[mt][r] *= inv;
        }

        // wave asum partial -> asb[w]
        #pragma unroll
        for (int mt = 0; mt < 4; ++mt)
            #pragma unroll
            for (int r = 0; r < 4; ++r) {
                float v = Lc[mt][r];
                v += __shfl_xor(v, 1);
                v += __shfl_xor(v, 2);
                v += __shfl_xor(v, 4);
                v += __shfl_xor(v, 8);
                if (l15 == 0) asb[w][16 * mt + 4 * q + r] = v;
            }

        // abar -> Ab (bf16), wave-private 16 columns
        #pragma unroll
        for (int mt = 0; mt < 4; ++mt)
            #pragma unroll
            for (int r = 0; r < 4; ++r) {
                __hip_bfloat16 hb = __float2bfloat16(Lc[mt][r]);
                short sv_; __builtin_memcpy(&sv_, &hb, 2);
                Ab[(16 * mt + 4 * q + r) * AB_S + 16 * w + l15] = sv_;
            }

        lds_barrier();   // xt, Ab, asb published; prefetched globals stay in flight

        // asum gather (once per window)
        if (t < KK) {
            float s = 0.f;
            #pragma unroll
            for (int ww = 0; ww < 8; ++ww) s += asb[ww][t];
            asumReg += s;
        }

        // ---- phase B: VLAD GEMM, 100% LDS (no vmcnt waits) ----
        // wave w owns d-tiles 2w, 2w+1: A-frag rows d = 32w + 16rg + l15
        #pragma unroll
        for (int s = 0; s < 4; ++s) {
            Frag Af0 = *(const Frag*)&UX.xt[(32 * w + l15) * XT_S + 32 * s + 8 * q];
            Frag Af1 = *(const Frag*)&UX.xt[(32 * w + 16 + l15) * XT_S + 32 * s + 8 * q];
            Frag Bf[4];
            #pragma unroll
            for (int ct = 0; ct < 4; ++ct)
                Bf[ct] = *(const Frag*)&Ab[(16 * ct + l15) * AB_S + 32 * s + 8 * q];
            #pragma unroll
            for (int ct = 0; ct < 4; ++ct) {
                acc[0][ct] = __builtin_amdgcn_mfma_f32_16x16x32_bf16(Af0.v, Bf[ct].v, acc[0][ct], 0, 0, 0);
                acc[1][ct] = __builtin_amdgcn_mfma_f32_16x16x32_bf16(Af1.v, Bf[ct].v, acc[1][ct], 0, 0, 0);
            }
        }

        lds_barrier();   // all waves done reading xt/Ab -> next window may overwrite
    }

    // ---- epilogue: asum + full V -> LDS -> plain coalesced stores ----
    if (t < KK) asum_part[(size_t)bid * KK + t] = asumReg;

    // acc element (rg, ct, r): k = 16ct + l15, d = 32w + 16rg + 4q + r
    #pragma unroll
    for (int rg = 0; rg < 2; ++rg)
        #pragma unroll
        for (int ct = 0; ct < 4; ++ct)
            #pragma unroll
            for (int r = 0; r < 4; ++r) {
                int k = 16 * ct + l15;
                int d = 32 * w + 16 * rg + 4 * q + r;
                UX.sv[k * SV_S + d] = acc[rg][ct][r];
            }
    __syncthreads();

    float* vout = Vpart + (size_t)bid * (KK * DD);
    #pragma unroll
    for (int ii = 0; ii < 32; ++ii) {
        int idx = t + BLOCK * ii;       // 0..16383
        vout[idx] = UX.sv[(idx >> 8) * SV_S + (idx & 255)];
    }
}

__global__ __launch_bounds__(256)
void netvlad_reduce(const float* __restrict__ Vpart, const float* __restrict__ asum_part,
                    float* __restrict__ Vred, float* __restrict__ asum_red)
{
    __shared__ float sbuf[256];
    const int t = threadIdx.x;
    if (blockIdx.x < 256) {
        const int o = blockIdx.x * 64 + (t & 63);
        const int g = t >> 6;
        float s = 0.f;
        #pragma unroll 8
        for (int i = 0; i < 64; ++i)
            s += Vpart[(size_t)(g * 64 + i) * (KK * DD) + o];
        sbuf[t] = s;
        __syncthreads();
        if (t < 64) Vred[o] = sbuf[t] + sbuf[t + 64] + sbuf[t + 128] + sbuf[t + 192];
    } else {
        const int k = t & 63;
        const int g = t >> 6;
        float s = 0.f;
        #pragma unroll 8
        for (int i = 0; i < 64; ++i)
            s += asum_part[(size_t)(g * 64 + i) * KK + k];
        sbuf[t] = s;
        __syncthreads();
        if (t < 64) asum_red[k] = sbuf[t] + sbuf[t + 64] + sbuf[t + 128] + sbuf[t + 192];
    }
}

__global__ __launch_bounds__(1024)
void netvlad_finalize(const float* __restrict__ Vws, const float* __restrict__ asum_ws,
                      const float* __restrict__ c, float* __restrict__ y)
{
    __shared__ float sV[KK * DD];
    __shared__ float sa[KK];
    __shared__ float colf[DD];
    __shared__ float rowf[KK];
    const int t = threadIdx.x;

    if (t < KK) sa[t] = asum_ws[t];
    __syncthreads();

    #pragma unroll
    for (int i = 0; i < 16; ++i) {
        int idx = t + 1024 * i;
        sV[idx] = Vws[idx] - c[idx] * sa[idx >> 8];
    }
    __syncthreads();

    if (t < DD) {   // column (d) norms over k
        float s = 0.f;
        for (int k = 0; k < KK; ++k) { float v = sV[k * DD + t]; s += v * v; }
        colf[t] = 1.0f / fmaxf(sqrtf(s), 1e-12f);
    }
    __syncthreads();

    #pragma unroll
    for (int i = 0; i < 16; ++i) {
        int idx = t + 1024 * i;
        sV[idx] *= colf[idx & 255];
    }
    __syncthreads();

    {   // row (k) norms over d: 16 threads per row
        int k = t >> 4, p = t & 15;
        float s = 0.f;
        #pragma unroll
        for (int j = 0; j < 16; ++j) { float v = sV[k * DD + p + 16 * j]; s += v * v; }
        s += __shfl_xor(s, 1);
        s += __shfl_xor(s, 2);
        s += __shfl_xor(s, 4);
        s += __shfl_xor(s, 8);
        if (p == 0) rowf[k] = 1.0f / fmaxf(sqrtf(s), 1e-12f);
    }
    __syncthreads();

    #pragma unroll
    for (int i = 0; i < 16; ++i) {
        int idx = t + 1024 * i;
        y[idx] = sV[idx] * rowf[idx >> 8];
    }
}

extern "C" void kernel_launch(void* const* d_in, const int* in_sizes, int n_in,
                              void* d_out, int out_size, void* d_ws, size_t ws_size,
                              hipStream_t stream) {
    const float* x      = (const float*)d_in[0];
    const float* c      = (const float*)d_in[1];
    const float* conv_w = (const float*)d_in[2];
    const float* conv_b = (const float*)d_in[3];
    float* y = (float*)d_out;

    // workspace: 256*16384 + 256*64 + 16384 + 64 floats (~16.9 MB)
    float* Vpart     = (float*)d_ws;
    float* asum_part = Vpart + (size_t)GRID * KK * DD;
    float* Vred      = asum_part + (size_t)GRID * KK;
    float* asum_red  = Vred + KK * DD;

    // no memset needed: all partials are fully overwritten with plain stores
    netvlad_fused<<<GRID, BLOCK, 0, stream>>>(x, conv_w, conv_b, Vpart, asum_part);
    netvlad_reduce<<<257, 256, 0, stream>>>(Vpart, asum_part, Vred, asum_red);
    netvlad_finalize<<<1, 1024, 0, stream>>>(Vred, asum_red, c, y);
}